// Round 16
// baseline (550.479 us; speedup 1.0000x reference)
//
#include <hip/hip_runtime.h>
#include <hip/hip_bf16.h>
#include <hip/hip_fp16.h>

#define NN 100000
#define EE 1600000
#define NB 98         // ceil(NN / 1024)
#define NPASS 2       // scatter destination passes
#define RNGD 50000    // NN / NPASS
#define NBUCK 8       // source-column buckets (sorted CSR improves row-local L2 reuse)
#define BUCKW 12500   // NN / NBUCK
#define NSPLIT 32     // stats atomic-split ways

typedef _Float16 f16x8 __attribute__((ext_vector_type(8)));
typedef _Float16 f16x4 __attribute__((ext_vector_type(4)));
typedef float f32x4 __attribute__((ext_vector_type(4)));

// ---------------- graph preprocessing ----------------

__global__ void k_init(int* __restrict__ cnt2, int* __restrict__ cursor2,
                       float* __restrict__ stats, int n8) {
    int i = blockIdx.x * blockDim.x + threadIdx.x;
    for (; i < n8; i += gridDim.x * blockDim.x) {
        cnt2[i] = 0;
        cursor2[i] = 0;
        if (i < 4 * 2 * NSPLIT * 128) stats[i] = 0.0f;   // 4 layers x {sum,sq} x 32 x 128
    }
}

// count per (row, col-bucket)
__global__ void k_count2(const int* __restrict__ ei, int* __restrict__ cnt2, int e_total) {
    int e = blockIdx.x * blockDim.x + threadIdx.x;
    for (; e < e_total; e += gridDim.x * blockDim.x) {
        int r = ei[e];
        int c = ei[e_total + e];
        atomicAdd(&cnt2[r * NBUCK + c / BUCKW], 1);
    }
}

// prep1: per 1024-node chunk -> cnt, dinv, bsum (chunk degree total),
// bhist (degree histogram, TRANSPOSED bhist[d*NB+blk])
__global__ __launch_bounds__(256) void k_prep1(const int* __restrict__ cnt2,
                                               int* __restrict__ cnt,
                                               float* __restrict__ dinv,
                                               int* __restrict__ bsum,
                                               int* __restrict__ bhist, int n) {
    __shared__ int hist[64];
    __shared__ int ws[4];
    int blk = blockIdx.x, tid = threadIdx.x;
    if (tid < 64) hist[tid] = 0;
    __syncthreads();
    int idx = blk * 1024 + tid * 4;
    int stot = 0;
    #pragma unroll
    for (int j = 0; j < 4; j++) {
        int node = idx + j;
        if (node < n) {
            int4 a = *(const int4*)&cnt2[node * 8];
            int4 b = *(const int4*)&cnt2[node * 8 + 4];
            int s = a.x + a.y + a.z + a.w + b.x + b.y + b.z + b.w;
            cnt[node] = s;
            dinv[node] = rsqrtf((float)(s + 1));
            atomicAdd(&hist[min(s, 63)], 1);
            stot += s;
        }
    }
    #pragma unroll
    for (int off = 32; off; off >>= 1) stot += __shfl_down(stot, off, 64);
    if ((tid & 63) == 0) ws[tid >> 6] = stot;
    __syncthreads();
    if (tid == 0) bsum[blk] = ws[0] + ws[1] + ws[2] + ws[3];
    if (tid < 64) bhist[tid * NB + blk] = hist[tid];
}

// prep2 (single block, 128 threads): scan bsum -> boff; scan bhist -> boff2, gstart
__global__ __launch_bounds__(128) void k_prep2(const int* __restrict__ bsum,
                                               const int* __restrict__ bhist,
                                               int* __restrict__ boff,
                                               int* __restrict__ boff2,
                                               int* __restrict__ gstart) {
    __shared__ int w0sum;
    int tid = threadIdx.x;
    int lane = tid & 63;
    {   // exclusive scan of NB block sums
        int v = (tid < NB) ? bsum[tid] : 0;
        int incl = v;
        #pragma unroll
        for (int off = 1; off < 64; off <<= 1) {
            int t = __shfl_up(incl, off, 64);
            if (lane >= off) incl += t;
        }
        if (tid == 63) w0sum = incl;
        __syncthreads();
        int excl = incl - v + ((tid >= 64) ? w0sum : 0);
        if (tid < NB) boff[tid] = excl;
    }
    if (tid < 64) {   // per-degree running offsets + global degree starts
        int d = tid;
        int running = 0;
        for (int b = 0; b < NB; b++) {
            int v = bhist[d * NB + b];
            boff2[b * 64 + d] = running;
            running += v;
        }
        int incl = running;
        #pragma unroll
        for (int off = 1; off < 64; off <<= 1) {
            int t = __shfl_up(incl, off, 64);
            if (d >= off) incl += t;
        }
        gstart[d] = incl - running;
    }
}

// prep3: per 1024-node chunk -> rowptr, rowptr2 (bucket offsets), order (counting sort)
__global__ __launch_bounds__(256) void k_prep3(const int* __restrict__ cnt,
                                               const int* __restrict__ cnt2,
                                               const int* __restrict__ boff,
                                               const int* __restrict__ boff2,
                                               const int* __restrict__ gstart,
                                               int* __restrict__ rowptr,
                                               int* __restrict__ rowptr2,
                                               int* __restrict__ order, int n) {
    __shared__ int wsum[4];
    __shared__ int cur[64];
    int blk = blockIdx.x, tid = threadIdx.x, lane = tid & 63, wid = tid >> 6;
    if (tid < 64) cur[tid] = 0;
    int idx = blk * 1024 + tid * 4;
    int c[4]; int s = 0;
    #pragma unroll
    for (int j = 0; j < 4; j++) { c[j] = (idx + j < n) ? cnt[idx + j] : 0; s += c[j]; }
    int incl = s;
    #pragma unroll
    for (int off = 1; off < 64; off <<= 1) {
        int t = __shfl_up(incl, off, 64);
        if (lane >= off) incl += t;
    }
    if (lane == 63) wsum[wid] = incl;
    __syncthreads();
    int wpre = 0;
    #pragma unroll
    for (int w = 0; w < 4; w++) if (w < wid) wpre += wsum[w];
    int base = boff[blk] + wpre + (incl - s);
    #pragma unroll
    for (int j = 0; j < 4; j++) {
        int node = idx + j;
        if (node < n) {
            int rstart = base;
            base += c[j];
            rowptr[node + 1] = base;
            int4 a = *(const int4*)&cnt2[node * 8];
            int4 b = *(const int4*)&cnt2[node * 8 + 4];
            int v[8] = {a.x, a.y, a.z, a.w, b.x, b.y, b.z, b.w};
            int o[8];
            #pragma unroll
            for (int i = 0; i < 8; i++) { o[i] = rstart; rstart += v[i]; }
            *(int4*)&rowptr2[node * 8]     = make_int4(o[0], o[1], o[2], o[3]);
            *(int4*)&rowptr2[node * 8 + 4] = make_int4(o[4], o[5], o[6], o[7]);
            if (node == n - 1) rowptr2[n * 8] = rstart;
        }
    }
    if (blk == 0 && tid == 0) rowptr[0] = 0;
    __syncthreads();
    #pragma unroll
    for (int j = 0; j < 4; j++) {
        int node = idx + j;
        if (node < n) {
            int d = min(c[j], 63);
            int r = atomicAdd(&cur[d], 1);
            order[gstart[d] + boff2[blk * 64 + d] + r] = node;
        }
    }
}

// scatter pass: destinations in [lo, lo+RNGD), into bucketed slots
__global__ void k_scatter_pass(const int* __restrict__ ei, const int* __restrict__ rowptr2,
                               int* __restrict__ cursor2, int* __restrict__ ccol,
                               int e_total, int lo) {
    int hi = lo + RNGD;
    int e = blockIdx.x * blockDim.x + threadIdx.x;
    for (; e < e_total; e += gridDim.x * blockDim.x) {
        int r = ei[e];
        if (r >= lo && r < hi) {
            int c = ei[e_total + e];
            int idx = r * NBUCK + c / BUCKW;
            int pos = rowptr2[idx] + atomicAdd(&cursor2[idx], 1);
            ccol[pos] = c;
        }
    }
}

// prep4: prescale x -> xs (blocks 0..390) and W^T fp16 for layers 1-3 (rest)
__global__ __launch_bounds__(256) void k_prep4(const float* __restrict__ x,
                                               const float* __restrict__ dinv,
                                               _Float16* __restrict__ xs,
                                               const float* __restrict__ W1,
                                               const float* __restrict__ W2,
                                               const float* __restrict__ W3,
                                               _Float16* __restrict__ wt16, int n) {
    int blk = blockIdx.x;
    if (blk < 391) {
        int node = blk * 256 + threadIdx.x;
        if (node >= n) return;
        float d = dinv[node];
        float4 a = ((const float4*)x)[node * 2];
        float4 b = ((const float4*)x)[node * 2 + 1];
        f16x8 o;
        o[0] = (_Float16)(a.x * d); o[1] = (_Float16)(a.y * d);
        o[2] = (_Float16)(a.z * d); o[3] = (_Float16)(a.w * d);
        o[4] = (_Float16)(b.x * d); o[5] = (_Float16)(b.y * d);
        o[6] = (_Float16)(b.z * d); o[7] = (_Float16)(b.w * d);
        ((f16x8*)xs)[node] = o;
    } else {
        int wi = (blk - 391) * 256 + threadIdx.x;   // 0..40959
        const float* W; _Float16* dst; int FI, local;
        if (wi < 8192)       { W = W1; dst = wt16;         FI = 64;  local = wi; }
        else if (wi < 24576) { W = W2; dst = wt16 + 8192;  FI = 128; local = wi - 8192; }
        else                 { W = W3; dst = wt16 + 24576; FI = 128; local = wi - 24576; }
        int k = local / 128, ch = local % 128;
        dst[ch * FI + k] = (_Float16)W[local];
    }
}

// ------- layer 0 SpMM: FI=8, one thread per node (degree-ordered) -------

__global__ __launch_bounds__(256) void k_spmm8(const _Float16* __restrict__ xs,
                                               const int* __restrict__ order,
                                               const int* __restrict__ rowptr,
                                               const int* __restrict__ ccol,
                                               const float* __restrict__ dinv,
                                               _Float16* __restrict__ aggh, int n) {
    int gid = blockIdx.x * 256 + threadIdx.x;
    if (gid >= n) return;
    int node = order[gid];
    int s = rowptr[node], e = rowptr[node + 1];
    const f16x8* x8 = (const f16x8*)xs;
    float acc[8];
    f16x8 self = x8[node];
    #pragma unroll
    for (int j = 0; j < 8; j++) acc[j] = (float)self[j];
    for (int k = s; k < e; k++) {
        f16x8 v = x8[ccol[k]];
        #pragma unroll
        for (int j = 0; j < 8; j++) acc[j] += (float)v[j];
    }
    float dr = dinv[node];
    f16x8 o;
    #pragma unroll
    for (int j = 0; j < 8; j++) o[j] = (_Float16)(acc[j] * dr);
    ((f16x8*)aggh)[node] = o;
}

// ---------------- small dense matmul (layer 0 only: FI=8, FO=64) ----------------

template <int FI, int FO>
__global__ __launch_bounds__(256) void k_mm(const _Float16* __restrict__ aggh,
                                            const float* __restrict__ W,
                                            const float* __restrict__ b,
                                            _Float16* __restrict__ hout,
                                            float* __restrict__ psum,
                                            float* __restrict__ psq, int n) {
    constexpr int NODES = 32;
    constexpr int KT = (FI * FO * 4 > 32768) ? FI / 2 : FI;
    constexpr int NPI = 256 / FO;
    __shared__ float wlds[KT * FO];
    __shared__ float alds[NODES * FI];
    __shared__ float red[2 * 256];

    int node0 = blockIdx.x * NODES;
    for (int idx = threadIdx.x; idx < NODES * FI / 8; idx += 256) {
        int gn = node0 + idx / (FI / 8);
        int kc = idx % (FI / 8);
        f16x8 v;
        #pragma unroll
        for (int j = 0; j < 8; j++) v[j] = (_Float16)0.f;
        if (gn < n) v = ((const f16x8*)aggh)[(size_t)gn * (FI / 8) + kc];
        float* dst = &alds[(idx / (FI / 8)) * FI + kc * 8];
        #pragma unroll
        for (int j = 0; j < 8; j++) dst[j] = (float)v[j];
    }

    int ch = threadIdx.x % FO;
    int ng = threadIdx.x / FO;
    float bb = b[ch];
    float accs[NODES / NPI];
    #pragma unroll
    for (int i = 0; i < NODES / NPI; i++) accs[i] = bb;

    for (int k0 = 0; k0 < FI; k0 += KT) {
        __syncthreads();
        for (int idx = threadIdx.x; idx < KT * FO; idx += 256)
            wlds[idx] = W[k0 * FO + idx];
        __syncthreads();
        #pragma unroll
        for (int i = 0; i < NODES / NPI; i++) {
            int nl = i * NPI + ng;
            float a = accs[i];
            #pragma unroll 4
            for (int k = 0; k < KT; k++)
                a += alds[nl * FI + k0 + k] * wlds[k * FO + ch];
            accs[i] = a;
        }
    }

    float sum = 0.f, sq = 0.f;
    #pragma unroll
    for (int i = 0; i < NODES / NPI; i++) {
        int nl = i * NPI + ng;
        int gn = node0 + nl;
        if (gn < n) hout[(size_t)gn * FO + ch] = (_Float16)accs[i];
        sum += accs[i];
        sq += accs[i] * accs[i];
    }
    red[threadIdx.x] = sum;
    red[256 + threadIdx.x] = sq;
    __syncthreads();
    if (threadIdx.x < FO) {
        float s = 0.f, q = 0.f;
        #pragma unroll
        for (int g = 0; g < NPI; g++) { s += red[g * FO + ch]; q += red[256 + g * FO + ch]; }
        int split = blockIdx.x & (NSPLIT - 1);
        atomicAdd(&psum[split * FO + ch], s);
        atomicAdd(&psq [split * FO + ch], q);
    }
}

// ---------------- FUSED gather + MFMA matmul, FO=128, FI in {64,128} ------------
// No W^T LDS tile: MFMA A-fragments read directly from global wt16 (32KB,
// L2/L1-resident, shared by all blocks). LDS = 4KB stats buffer only ->
// occupancy is VGPR-limited; __launch_bounds__(256,6) caps at 84 VGPR (body
// needs ~60, no spill). 256 threads, ascending sorted-contiguous nodes.

template <int FI>
__global__ __launch_bounds__(256, 6) void k_fused(const _Float16* __restrict__ h,
                                                  const int* __restrict__ order,
                                                  const int* __restrict__ rowptr,
                                                  const int* __restrict__ ccol,
                                                  const float* __restrict__ dinv,
                                                  const _Float16* __restrict__ wt16,
                                                  const float* __restrict__ b,
                                                  _Float16* __restrict__ hout,
                                                  float* __restrict__ psum,
                                                  float* __restrict__ psq, int n) {
    constexpr int KS = FI / 32;          // K-steps of 32
    constexpr int TPN = FI / 8;          // 16B chunks per row
    __shared__ float red[2 * 4 * 128];   // 4KB stats buffer

    const int tid = threadIdx.x;
    const int wv  = tid >> 6;
    const int ln  = tid & 63;
    const int l15 = ln & 15;
    const int lh  = ln >> 4;             // 0..3

    const int gid = blockIdx.x * 64 + wv * 16 + l15;
    const bool v0 = (gid < n);
    const int node = v0 ? order[gid] : 0;
    const f16x8* h8 = (const f16x8*)h;

    // gather aggregation in fp32, B-frag layout (k = kk*32 + lh*8 + j)
    float ga[KS][8];
    int s = 0, e = 0;
    if (v0) { s = rowptr[node]; e = rowptr[node + 1]; }
    #pragma unroll
    for (int kk = 0; kk < KS; kk++) {       // self contribution
        f16x8 v = {};
        if (v0) v = h8[(size_t)node * TPN + kk * 4 + lh];
        #pragma unroll
        for (int j = 0; j < 8; j++) ga[kk][j] = (float)v[j];
    }
    for (int k = s; k < e; k++) {
        int c = ccol[k];
        #pragma unroll
        for (int kk = 0; kk < KS; kk++) {
            f16x8 v = h8[(size_t)c * TPN + kk * 4 + lh];
            #pragma unroll
            for (int j = 0; j < 8; j++) ga[kk][j] += (float)v[j];
        }
    }
    float dr = v0 ? dinv[node] : 0.f;
    f16x8 bf[KS];
    #pragma unroll
    for (int kk = 0; kk < KS; kk++) {
        #pragma unroll
        for (int j = 0; j < 8; j++) bf[kk][j] = (_Float16)(ga[kk][j] * dr);
    }

    // acc init = bias (ch = t*16 + lh*4 + r)
    f32x4 acc[8];
    #pragma unroll
    for (int t = 0; t < 8; t++) acc[t] = *(const f32x4*)&b[t * 16 + lh * 4];

    // MFMA: A-fragments straight from global (L2-hot wt16)
    #pragma unroll
    for (int kk = 0; kk < KS; kk++) {
        #pragma unroll
        for (int t = 0; t < 8; t++) {
            f16x8 af = *(const f16x8*)&wt16[(size_t)(t * 16 + l15) * FI + kk * 32 + lh * 8];
            acc[t] = __builtin_amdgcn_mfma_f32_16x16x32_f16(af, bf[kk], acc[t], 0, 0, 0);
        }
    }

    // stores
    if (v0) {
        #pragma unroll
        for (int t = 0; t < 8; t++) {
            f16x4 o;
            #pragma unroll
            for (int r = 0; r < 4; r++) o[r] = (_Float16)acc[t][r];
            ((f16x4*)hout)[(size_t)node * 32 + t * 4 + lh] = o;
        }
    }

    // stats
    #pragma unroll
    for (int t = 0; t < 8; t++) {
        f32x4 sv = {0.f, 0.f, 0.f, 0.f}, qv = {0.f, 0.f, 0.f, 0.f};
        if (v0) { sv = acc[t]; qv = acc[t] * acc[t]; }
        #pragma unroll
        for (int m = 1; m < 16; m <<= 1) {
            #pragma unroll
            for (int r = 0; r < 4; r++) {
                sv[r] += __shfl_xor(sv[r], m, 64);
                qv[r] += __shfl_xor(qv[r], m, 64);
            }
        }
        if (l15 == 0) {
            *(f32x4*)&red[wv * 128 + t * 16 + lh * 4] = sv;
            *(f32x4*)&red[512 + wv * 128 + t * 16 + lh * 4] = qv;
        }
    }
    __syncthreads();
    if (tid < 128) {
        float ss = red[tid] + red[128 + tid] + red[256 + tid] + red[384 + tid];
        float qq = red[512 + tid] + red[640 + tid] + red[768 + tid] + red[896 + tid];
        int split = blockIdx.x & (NSPLIT - 1);
        atomicAdd(&psum[split * 128 + tid], ss);
        atomicAdd(&psq [split * 128 + tid], qq);
    }
}

// ------- norm + tanh with INLINE coef (each block reduces the 32 partial rows;
// L2-hot 16KB read). Non-final layers pre-scale by dinv; final writes fp32. -------

template <bool OUT32, int FO>
__global__ __launch_bounds__(256) void k_normc(_Float16* __restrict__ h,
                                               float* __restrict__ out32,
                                               const float* __restrict__ psum,
                                               const float* __restrict__ psq,
                                               const float* __restrict__ gw,
                                               const float* __restrict__ gb,
                                               const float* __restrict__ gm,
                                               const float* __restrict__ dinv,
                                               int nchunks) {
    __shared__ float ssc[128], ssh[128];
    if (threadIdx.x < FO) {
        int ch = threadIdx.x;
        float s = 0.f, q = 0.f;
        #pragma unroll 8
        for (int r = 0; r < NSPLIT; r++) {
            s += psum[r * FO + ch];
            q += psq[r * FO + ch];
        }
        float invn = 1.0f / (float)NN;
        float m = s * invn;
        float msq = q * invn;
        float g = gm[ch];
        float var = msq - 2.f * g * m * m + g * g * m * m;
        float sc = gw[ch] * rsqrtf(var + 1e-5f);
        ssc[ch] = sc;
        ssh[ch] = gb[ch] - sc * g * m;
    }
    __syncthreads();
    int i = blockIdx.x * blockDim.x + threadIdx.x;
    f16x8* h8 = (f16x8*)h;
    for (; i < nchunks; i += gridDim.x * blockDim.x) {
        f16x8 v = h8[i];
        int ch0 = (i * 8) & (FO - 1);
        float r[8];
        #pragma unroll
        for (int j = 0; j < 8; j++)
            r[j] = tanhf(ssc[ch0 + j] * (float)v[j] + ssh[ch0 + j]);
        if (OUT32) {
            ((float4*)out32)[i * 2]     = make_float4(r[0], r[1], r[2], r[3]);
            ((float4*)out32)[i * 2 + 1] = make_float4(r[4], r[5], r[6], r[7]);
        } else {
            float d = dinv[i / (FO / 8)];
            f16x8 o;
            #pragma unroll
            for (int j = 0; j < 8; j++) o[j] = (_Float16)(r[j] * d);
            h8[i] = o;
        }
    }
}

// ---------------- host side ----------------

static inline int ceil_div(int a, int b) { return (a + b - 1) / b; }

extern "C" void kernel_launch(void* const* d_in, const int* in_sizes, int n_in,
                              void* d_out, int out_size, void* d_ws, size_t ws_size,
                              hipStream_t stream) {
    const float* x = (const float*)d_in[0];
    const int* ei = (const int*)d_in[1];
    const float *Wp[4], *bp[4], *gwp[4], *gbp[4], *gmp[4];
    for (int i = 0; i < 4; i++) {
        Wp[i]  = (const float*)d_in[3 + 5 * i];
        bp[i]  = (const float*)d_in[4 + 5 * i];
        gwp[i] = (const float*)d_in[5 + 5 * i];
        gbp[i] = (const float*)d_in[6 + 5 * i];
        gmp[i] = (const float*)d_in[7 + 5 * i];
    }
    float* out = (float*)d_out;

    const int NT0 = ceil_div(NN, 32);    // 3125 layer-0 matmul blocks
    const int NTF = ceil_div(NN, 64);    // 1563 fused blocks (256 threads)

    char* p = (char*)d_ws;
    auto alloc = [&](size_t bytes) {
        void* q = (void*)p;
        p += (bytes + 255) / 256 * 256;
        return q;
    };
    int*      cnt2    = (int*)alloc((size_t)NN * 8 * 4);
    int*      cursor2 = (int*)alloc((size_t)NN * 8 * 4);
    int*      rowptr2 = (int*)alloc(((size_t)NN * 8 + 1) * 4);
    int*      cnt     = (int*)alloc((size_t)NN * 4);
    int*      rowptr  = (int*)alloc((size_t)(NN + 1) * 4);
    float*    dinv    = (float*)alloc((size_t)NN * 4);
    int*      ccol    = (int*)alloc((size_t)EE * 4);
    int*      bsum    = (int*)alloc((size_t)NB * 4);
    int*      boff    = (int*)alloc((size_t)NB * 4);
    int*      bhist   = (int*)alloc((size_t)NB * 64 * 4);
    int*      boff2   = (int*)alloc((size_t)NB * 64 * 4);
    int*      gstart  = (int*)alloc((size_t)64 * 4);
    int*      order   = (int*)alloc((size_t)NN * 4);
    float*    stats   = (float*)alloc((size_t)4 * 2 * NSPLIT * 128 * 4);
    _Float16* wt16    = (_Float16*)alloc((size_t)(128 * 64 + 2 * 128 * 128) * 2);
    _Float16* xs      = (_Float16*)alloc((size_t)NN * 8 * 2);
    _Float16* aggh    = (_Float16*)alloc((size_t)NN * 64 * 2);   // layer-0 agg only
    _Float16* hA      = (_Float16*)alloc((size_t)NN * 128 * 2);
    _Float16* hB      = (_Float16*)alloc((size_t)NN * 128 * 2);
    _Float16* wt16a   = wt16;
    _Float16* wt16b   = wt16 + 8192;
    _Float16* wt16c   = wt16 + 24576;

    // preprocessing (8 dispatches)
    k_init<<<512, 256, 0, stream>>>(cnt2, cursor2, stats, NN * 8);
    k_count2<<<2048, 256, 0, stream>>>(ei, cnt2, EE);
    k_prep1<<<NB, 256, 0, stream>>>(cnt2, cnt, dinv, bsum, bhist, NN);
    k_prep2<<<1, 128, 0, stream>>>(bsum, bhist, boff, boff2, gstart);
    k_prep3<<<NB, 256, 0, stream>>>(cnt, cnt2, boff, boff2, gstart, rowptr, rowptr2, order, NN);
    for (int pass = 0; pass < NPASS; pass++)
        k_scatter_pass<<<1024, 256, 0, stream>>>(ei, rowptr2, cursor2, ccol, EE, pass * RNGD);
    k_prep4<<<391 + 160, 256, 0, stream>>>(x, dinv, xs, Wp[1], Wp[2], Wp[3], wt16, NN);

    // layers (intermediates fp16, pre-scaled by dinv except final output)
    {   // layer 0: xs(8) -> aggh(8) -> hA(64)
        float* sp = stats + 0 * 2 * NSPLIT * 128;
        float* sq = sp + NSPLIT * 128;
        k_spmm8<<<ceil_div(NN, 256), 256, 0, stream>>>(xs, order, rowptr, ccol, dinv, aggh, NN);
        k_mm<8, 64><<<NT0, 256, 0, stream>>>(aggh, Wp[0], bp[0], hA, sp, sq, NN);
        k_normc<false, 64><<<1024, 256, 0, stream>>>(hA, nullptr, sp, sq, gwp[0], gbp[0], gmp[0], dinv, NN * 64 / 8);
    }
    {   // layer 1: hA(64) --fused gather+mfma--> hB(128)
        float* sp = stats + 1 * 2 * NSPLIT * 128;
        float* sq = sp + NSPLIT * 128;
        k_fused<64><<<NTF, 256, 0, stream>>>(hA, order, rowptr, ccol, dinv, wt16a, bp[1], hB, sp, sq, NN);
        k_normc<false, 128><<<1024, 256, 0, stream>>>(hB, nullptr, sp, sq, gwp[1], gbp[1], gmp[1], dinv, NN * 128 / 8);
    }
    {   // layer 2: hB(128) --fused--> hA(128)
        float* sp = stats + 2 * 2 * NSPLIT * 128;
        float* sq = sp + NSPLIT * 128;
        k_fused<128><<<NTF, 256, 0, stream>>>(hB, order, rowptr, ccol, dinv, wt16b, bp[2], hA, sp, sq, NN);
        k_normc<false, 128><<<1024, 256, 0, stream>>>(hA, nullptr, sp, sq, gwp[2], gbp[2], gmp[2], dinv, NN * 128 / 8);
    }
    {   // layer 3: hA(128) --fused--> hB(128) -> d_out (fp32, unscaled)
        float* sp = stats + 3 * 2 * NSPLIT * 128;
        float* sq = sp + NSPLIT * 128;
        k_fused<128><<<NTF, 256, 0, stream>>>(hA, order, rowptr, ccol, dinv, wt16c, bp[3], hB, sp, sq, NN);
        k_normc<true, 128><<<1024, 256, 0, stream>>>(hB, out, sp, sq, gwp[3], gbp[3], gmp[3], dinv, NN * 128 / 8);
    }
}

// Round 17
// 494.432 us; speedup vs baseline: 1.1134x; 1.1134x over previous
//
#include <hip/hip_runtime.h>
#include <hip/hip_bf16.h>
#include <hip/hip_fp16.h>

#define NN 100000
#define EE 1600000
#define NB 98         // ceil(NN / 1024)
#define NPASS 2       // scatter destination passes
#define RNGD 50000    // NN / NPASS
#define NBUCK 8       // source-column buckets (sorted CSR improves row-local L2 reuse)
#define BUCKW 12500   // NN / NBUCK
#define NSPLIT 32     // stats atomic-split ways

typedef _Float16 f16x8 __attribute__((ext_vector_type(8)));
typedef _Float16 f16x4 __attribute__((ext_vector_type(4)));
typedef float f32x4 __attribute__((ext_vector_type(4)));

// ---------------- graph preprocessing ----------------

__global__ void k_init(int* __restrict__ cnt2, int* __restrict__ cursor2,
                       float* __restrict__ stats, int n8) {
    int i = blockIdx.x * blockDim.x + threadIdx.x;
    for (; i < n8; i += gridDim.x * blockDim.x) {
        cnt2[i] = 0;
        cursor2[i] = 0;
        if (i < 4 * 2 * NSPLIT * 128) stats[i] = 0.0f;   // 4 layers x {sum,sq} x 32 x 128
    }
}

// count per (row, col-bucket)
__global__ void k_count2(const int* __restrict__ ei, int* __restrict__ cnt2, int e_total) {
    int e = blockIdx.x * blockDim.x + threadIdx.x;
    for (; e < e_total; e += gridDim.x * blockDim.x) {
        int r = ei[e];
        int c = ei[e_total + e];
        atomicAdd(&cnt2[r * NBUCK + c / BUCKW], 1);
    }
}

// prep1: per 1024-node chunk -> cnt, dinv, bsum (chunk degree total),
// bhist (degree histogram, TRANSPOSED bhist[d*NB+blk])
__global__ __launch_bounds__(256) void k_prep1(const int* __restrict__ cnt2,
                                               int* __restrict__ cnt,
                                               float* __restrict__ dinv,
                                               int* __restrict__ bsum,
                                               int* __restrict__ bhist, int n) {
    __shared__ int hist[64];
    __shared__ int ws[4];
    int blk = blockIdx.x, tid = threadIdx.x;
    if (tid < 64) hist[tid] = 0;
    __syncthreads();
    int idx = blk * 1024 + tid * 4;
    int stot = 0;
    #pragma unroll
    for (int j = 0; j < 4; j++) {
        int node = idx + j;
        if (node < n) {
            int4 a = *(const int4*)&cnt2[node * 8];
            int4 b = *(const int4*)&cnt2[node * 8 + 4];
            int s = a.x + a.y + a.z + a.w + b.x + b.y + b.z + b.w;
            cnt[node] = s;
            dinv[node] = rsqrtf((float)(s + 1));
            atomicAdd(&hist[min(s, 63)], 1);
            stot += s;
        }
    }
    #pragma unroll
    for (int off = 32; off; off >>= 1) stot += __shfl_down(stot, off, 64);
    if ((tid & 63) == 0) ws[tid >> 6] = stot;
    __syncthreads();
    if (tid == 0) bsum[blk] = ws[0] + ws[1] + ws[2] + ws[3];
    if (tid < 64) bhist[tid * NB + blk] = hist[tid];
}

// prep2 (single block, 128 threads): scan bsum -> boff; scan bhist -> boff2, gstart
__global__ __launch_bounds__(128) void k_prep2(const int* __restrict__ bsum,
                                               const int* __restrict__ bhist,
                                               int* __restrict__ boff,
                                               int* __restrict__ boff2,
                                               int* __restrict__ gstart) {
    __shared__ int w0sum;
    int tid = threadIdx.x;
    int lane = tid & 63;
    {   // exclusive scan of NB block sums
        int v = (tid < NB) ? bsum[tid] : 0;
        int incl = v;
        #pragma unroll
        for (int off = 1; off < 64; off <<= 1) {
            int t = __shfl_up(incl, off, 64);
            if (lane >= off) incl += t;
        }
        if (tid == 63) w0sum = incl;
        __syncthreads();
        int excl = incl - v + ((tid >= 64) ? w0sum : 0);
        if (tid < NB) boff[tid] = excl;
    }
    if (tid < 64) {   // per-degree running offsets + global degree starts
        int d = tid;
        int running = 0;
        for (int b = 0; b < NB; b++) {
            int v = bhist[d * NB + b];
            boff2[b * 64 + d] = running;
            running += v;
        }
        int incl = running;
        #pragma unroll
        for (int off = 1; off < 64; off <<= 1) {
            int t = __shfl_up(incl, off, 64);
            if (d >= off) incl += t;
        }
        gstart[d] = incl - running;
    }
}

// prep3: per 1024-node chunk -> rowptr, rowptr2 (bucket offsets), order (counting sort)
__global__ __launch_bounds__(256) void k_prep3(const int* __restrict__ cnt,
                                               const int* __restrict__ cnt2,
                                               const int* __restrict__ boff,
                                               const int* __restrict__ boff2,
                                               const int* __restrict__ gstart,
                                               int* __restrict__ rowptr,
                                               int* __restrict__ rowptr2,
                                               int* __restrict__ order, int n) {
    __shared__ int wsum[4];
    __shared__ int cur[64];
    int blk = blockIdx.x, tid = threadIdx.x, lane = tid & 63, wid = tid >> 6;
    if (tid < 64) cur[tid] = 0;
    int idx = blk * 1024 + tid * 4;
    int c[4]; int s = 0;
    #pragma unroll
    for (int j = 0; j < 4; j++) { c[j] = (idx + j < n) ? cnt[idx + j] : 0; s += c[j]; }
    int incl = s;
    #pragma unroll
    for (int off = 1; off < 64; off <<= 1) {
        int t = __shfl_up(incl, off, 64);
        if (lane >= off) incl += t;
    }
    if (lane == 63) wsum[wid] = incl;
    __syncthreads();
    int wpre = 0;
    #pragma unroll
    for (int w = 0; w < 4; w++) if (w < wid) wpre += wsum[w];
    int base = boff[blk] + wpre + (incl - s);
    #pragma unroll
    for (int j = 0; j < 4; j++) {
        int node = idx + j;
        if (node < n) {
            int rstart = base;
            base += c[j];
            rowptr[node + 1] = base;
            int4 a = *(const int4*)&cnt2[node * 8];
            int4 b = *(const int4*)&cnt2[node * 8 + 4];
            int v[8] = {a.x, a.y, a.z, a.w, b.x, b.y, b.z, b.w};
            int o[8];
            #pragma unroll
            for (int i = 0; i < 8; i++) { o[i] = rstart; rstart += v[i]; }
            *(int4*)&rowptr2[node * 8]     = make_int4(o[0], o[1], o[2], o[3]);
            *(int4*)&rowptr2[node * 8 + 4] = make_int4(o[4], o[5], o[6], o[7]);
            if (node == n - 1) rowptr2[n * 8] = rstart;
        }
    }
    if (blk == 0 && tid == 0) rowptr[0] = 0;
    __syncthreads();
    #pragma unroll
    for (int j = 0; j < 4; j++) {
        int node = idx + j;
        if (node < n) {
            int d = min(c[j], 63);
            int r = atomicAdd(&cur[d], 1);
            order[gstart[d] + boff2[blk * 64 + d] + r] = node;
        }
    }
}

// scatter pass: destinations in [lo, lo+RNGD), into bucketed slots
__global__ void k_scatter_pass(const int* __restrict__ ei, const int* __restrict__ rowptr2,
                               int* __restrict__ cursor2, int* __restrict__ ccol,
                               int e_total, int lo) {
    int hi = lo + RNGD;
    int e = blockIdx.x * blockDim.x + threadIdx.x;
    for (; e < e_total; e += gridDim.x * blockDim.x) {
        int r = ei[e];
        if (r >= lo && r < hi) {
            int c = ei[e_total + e];
            int idx = r * NBUCK + c / BUCKW;
            int pos = rowptr2[idx] + atomicAdd(&cursor2[idx], 1);
            ccol[pos] = c;
        }
    }
}

// prep4: prescale x -> xs (blocks 0..390) and W^T fp16 for layers 1-3 (rest)
__global__ __launch_bounds__(256) void k_prep4(const float* __restrict__ x,
                                               const float* __restrict__ dinv,
                                               _Float16* __restrict__ xs,
                                               const float* __restrict__ W1,
                                               const float* __restrict__ W2,
                                               const float* __restrict__ W3,
                                               _Float16* __restrict__ wt16, int n) {
    int blk = blockIdx.x;
    if (blk < 391) {
        int node = blk * 256 + threadIdx.x;
        if (node >= n) return;
        float d = dinv[node];
        float4 a = ((const float4*)x)[node * 2];
        float4 b = ((const float4*)x)[node * 2 + 1];
        f16x8 o;
        o[0] = (_Float16)(a.x * d); o[1] = (_Float16)(a.y * d);
        o[2] = (_Float16)(a.z * d); o[3] = (_Float16)(a.w * d);
        o[4] = (_Float16)(b.x * d); o[5] = (_Float16)(b.y * d);
        o[6] = (_Float16)(b.z * d); o[7] = (_Float16)(b.w * d);
        ((f16x8*)xs)[node] = o;
    } else {
        int wi = (blk - 391) * 256 + threadIdx.x;   // 0..40959
        const float* W; _Float16* dst; int FI, local;
        if (wi < 8192)       { W = W1; dst = wt16;         FI = 64;  local = wi; }
        else if (wi < 24576) { W = W2; dst = wt16 + 8192;  FI = 128; local = wi - 8192; }
        else                 { W = W3; dst = wt16 + 24576; FI = 128; local = wi - 24576; }
        int k = local / 128, ch = local % 128;
        dst[ch * FI + k] = (_Float16)W[local];
    }
}

// ------- layer 0 SpMM: FI=8, one thread per node (degree-ordered) -------

__global__ __launch_bounds__(256) void k_spmm8(const _Float16* __restrict__ xs,
                                               const int* __restrict__ order,
                                               const int* __restrict__ rowptr,
                                               const int* __restrict__ ccol,
                                               const float* __restrict__ dinv,
                                               _Float16* __restrict__ aggh, int n) {
    int gid = blockIdx.x * 256 + threadIdx.x;
    if (gid >= n) return;
    int node = order[gid];
    int s = rowptr[node], e = rowptr[node + 1];
    const f16x8* x8 = (const f16x8*)xs;
    float acc[8];
    f16x8 self = x8[node];
    #pragma unroll
    for (int j = 0; j < 8; j++) acc[j] = (float)self[j];
    for (int k = s; k < e; k++) {
        f16x8 v = x8[ccol[k]];
        #pragma unroll
        for (int j = 0; j < 8; j++) acc[j] += (float)v[j];
    }
    float dr = dinv[node];
    f16x8 o;
    #pragma unroll
    for (int j = 0; j < 8; j++) o[j] = (_Float16)(acc[j] * dr);
    ((f16x8*)aggh)[node] = o;
}

// ---------------- small dense matmul (layer 0 only: FI=8, FO=64) ----------------

template <int FI, int FO>
__global__ __launch_bounds__(256) void k_mm(const _Float16* __restrict__ aggh,
                                            const float* __restrict__ W,
                                            const float* __restrict__ b,
                                            _Float16* __restrict__ hout,
                                            float* __restrict__ psum,
                                            float* __restrict__ psq, int n) {
    constexpr int NODES = 32;
    constexpr int KT = (FI * FO * 4 > 32768) ? FI / 2 : FI;
    constexpr int NPI = 256 / FO;
    __shared__ float wlds[KT * FO];
    __shared__ float alds[NODES * FI];
    __shared__ float red[2 * 256];

    int node0 = blockIdx.x * NODES;
    for (int idx = threadIdx.x; idx < NODES * FI / 8; idx += 256) {
        int gn = node0 + idx / (FI / 8);
        int kc = idx % (FI / 8);
        f16x8 v;
        #pragma unroll
        for (int j = 0; j < 8; j++) v[j] = (_Float16)0.f;
        if (gn < n) v = ((const f16x8*)aggh)[(size_t)gn * (FI / 8) + kc];
        float* dst = &alds[(idx / (FI / 8)) * FI + kc * 8];
        #pragma unroll
        for (int j = 0; j < 8; j++) dst[j] = (float)v[j];
    }

    int ch = threadIdx.x % FO;
    int ng = threadIdx.x / FO;
    float bb = b[ch];
    float accs[NODES / NPI];
    #pragma unroll
    for (int i = 0; i < NODES / NPI; i++) accs[i] = bb;

    for (int k0 = 0; k0 < FI; k0 += KT) {
        __syncthreads();
        for (int idx = threadIdx.x; idx < KT * FO; idx += 256)
            wlds[idx] = W[k0 * FO + idx];
        __syncthreads();
        #pragma unroll
        for (int i = 0; i < NODES / NPI; i++) {
            int nl = i * NPI + ng;
            float a = accs[i];
            #pragma unroll 4
            for (int k = 0; k < KT; k++)
                a += alds[nl * FI + k0 + k] * wlds[k * FO + ch];
            accs[i] = a;
        }
    }

    float sum = 0.f, sq = 0.f;
    #pragma unroll
    for (int i = 0; i < NODES / NPI; i++) {
        int nl = i * NPI + ng;
        int gn = node0 + nl;
        if (gn < n) hout[(size_t)gn * FO + ch] = (_Float16)accs[i];
        sum += accs[i];
        sq += accs[i] * accs[i];
    }
    red[threadIdx.x] = sum;
    red[256 + threadIdx.x] = sq;
    __syncthreads();
    if (threadIdx.x < FO) {
        float s = 0.f, q = 0.f;
        #pragma unroll
        for (int g = 0; g < NPI; g++) { s += red[g * FO + ch]; q += red[256 + g * FO + ch]; }
        int split = blockIdx.x & (NSPLIT - 1);
        atomicAdd(&psum[split * FO + ch], s);
        atomicAdd(&psq [split * FO + ch], q);
    }
}

// ---------------- FUSED gather + MFMA matmul, FO=128, FI in {64,128} ------------
// r14 configuration (measured best: fused<128>=90us) + edge-loop unroll x2
// (isolated MLP probe; waves are equal-degree so the unroll is divergence-free).
// W^T fp16 staged coalesced into XOR-swizzled LDS (32KB, conflict-free);
// stats 'red' buffer aliases wt after the last MFMA read.

template <int FI>
__global__ __launch_bounds__(256) void k_fused(const _Float16* __restrict__ h,
                                               const int* __restrict__ order,
                                               const int* __restrict__ rowptr,
                                               const int* __restrict__ ccol,
                                               const float* __restrict__ dinv,
                                               const _Float16* __restrict__ wt16,
                                               const float* __restrict__ b,
                                               _Float16* __restrict__ hout,
                                               float* __restrict__ psum,
                                               float* __restrict__ psq, int n) {
    constexpr int KS = FI / 32;          // K-steps of 32
    constexpr int TPN = FI / 8;          // 16B chunks per row
    __shared__ _Float16 wt[128 * FI];    // swizzled W^T; aliased as red later

    const int tid = threadIdx.x;
    const int wv  = tid >> 6;
    const int ln  = tid & 63;
    const int l15 = ln & 15;
    const int lh  = ln >> 4;             // 0..3

    // stage swizzled W^T (coalesced 16B copies)
    {
        const f16x8* wg = (const f16x8*)wt16;
        f16x8* wl = (f16x8*)wt;
        for (int idx = tid; idx < 128 * TPN; idx += 256) {
            int ch = idx / TPN, c = idx % TPN;
            wl[ch * TPN + (c ^ (ch & 7))] = wg[idx];
        }
    }

    const int gid = blockIdx.x * 64 + wv * 16 + l15;
    const bool v0 = (gid < n);
    const int node = v0 ? order[gid] : 0;
    const f16x8* h8 = (const f16x8*)h;

    // gather aggregation in fp32, B-frag layout (k = kk*32 + lh*8 + j)
    float ga[KS][8];
    int s = 0, e = 0;
    if (v0) { s = rowptr[node]; e = rowptr[node + 1]; }
    #pragma unroll
    for (int kk = 0; kk < KS; kk++) {       // self contribution
        f16x8 v = {};
        if (v0) v = h8[(size_t)node * TPN + kk * 4 + lh];
        #pragma unroll
        for (int j = 0; j < 8; j++) ga[kk][j] = (float)v[j];
    }
    int k = s;
    for (; k + 2 <= e; k += 2) {            // unroll x2 for MLP (equal-degree waves)
        int c0 = ccol[k];
        int c1 = ccol[k + 1];
        #pragma unroll
        for (int kk = 0; kk < KS; kk++) {
            f16x8 va = h8[(size_t)c0 * TPN + kk * 4 + lh];
            f16x8 vb = h8[(size_t)c1 * TPN + kk * 4 + lh];
            #pragma unroll
            for (int j = 0; j < 8; j++) ga[kk][j] += (float)va[j] + (float)vb[j];
        }
    }
    if (k < e) {
        int c0 = ccol[k];
        #pragma unroll
        for (int kk = 0; kk < KS; kk++) {
            f16x8 va = h8[(size_t)c0 * TPN + kk * 4 + lh];
            #pragma unroll
            for (int j = 0; j < 8; j++) ga[kk][j] += (float)va[j];
        }
    }
    float dr = v0 ? dinv[node] : 0.f;
    f16x8 bf[KS];
    #pragma unroll
    for (int kk = 0; kk < KS; kk++) {
        #pragma unroll
        for (int j = 0; j < 8; j++) bf[kk][j] = (_Float16)(ga[kk][j] * dr);
    }

    // acc init = bias (ch = t*16 + lh*4 + r)
    f32x4 acc[8];
    #pragma unroll
    for (int t = 0; t < 8; t++) acc[t] = *(const f32x4*)&b[t * 16 + lh * 4];

    __syncthreads();   // wt staged

    #pragma unroll
    for (int kk = 0; kk < KS; kk++) {
        #pragma unroll
        for (int t = 0; t < 8; t++) {
            f16x8 af = ((const f16x8*)wt)[(t * 16 + l15) * TPN + ((kk * 4 + lh) ^ (l15 & 7))];
            acc[t] = __builtin_amdgcn_mfma_f32_16x16x32_f16(af, bf[kk], acc[t], 0, 0, 0);
        }
    }

    // stores (no LDS involved)
    if (v0) {
        #pragma unroll
        for (int t = 0; t < 8; t++) {
            f16x4 o;
            #pragma unroll
            for (int r = 0; r < 4; r++) o[r] = (_Float16)acc[t][r];
            ((f16x4*)hout)[(size_t)node * 32 + t * 4 + lh] = o;
        }
    }

    __syncthreads();   // all wt reads done -> safe to alias as red
    float* red = (float*)wt;   // [2][4][128] floats = 4KB
    #pragma unroll
    for (int t = 0; t < 8; t++) {
        f32x4 sv = {0.f, 0.f, 0.f, 0.f}, qv = {0.f, 0.f, 0.f, 0.f};
        if (v0) { sv = acc[t]; qv = acc[t] * acc[t]; }
        #pragma unroll
        for (int m = 1; m < 16; m <<= 1) {
            #pragma unroll
            for (int r = 0; r < 4; r++) {
                sv[r] += __shfl_xor(sv[r], m, 64);
                qv[r] += __shfl_xor(qv[r], m, 64);
            }
        }
        if (l15 == 0) {
            *(f32x4*)&red[wv * 128 + t * 16 + lh * 4] = sv;
            *(f32x4*)&red[512 + wv * 128 + t * 16 + lh * 4] = qv;
        }
    }
    __syncthreads();
    if (tid < 128) {
        float ss = red[tid] + red[128 + tid] + red[256 + tid] + red[384 + tid];
        float qq = red[512 + tid] + red[640 + tid] + red[768 + tid] + red[896 + tid];
        int split = blockIdx.x & (NSPLIT - 1);
        atomicAdd(&psum[split * 128 + tid], ss);
        atomicAdd(&psq [split * 128 + tid], qq);
    }
}

// ------- norm + tanh with INLINE coef (each block reduces the 32 partial rows;
// L2-hot 16KB read). Non-final layers pre-scale by dinv; final writes fp32. -------

template <bool OUT32, int FO>
__global__ __launch_bounds__(256) void k_normc(_Float16* __restrict__ h,
                                               float* __restrict__ out32,
                                               const float* __restrict__ psum,
                                               const float* __restrict__ psq,
                                               const float* __restrict__ gw,
                                               const float* __restrict__ gb,
                                               const float* __restrict__ gm,
                                               const float* __restrict__ dinv,
                                               int nchunks) {
    __shared__ float ssc[128], ssh[128];
    if (threadIdx.x < FO) {
        int ch = threadIdx.x;
        float s = 0.f, q = 0.f;
        #pragma unroll 8
        for (int r = 0; r < NSPLIT; r++) {
            s += psum[r * FO + ch];
            q += psq[r * FO + ch];
        }
        float invn = 1.0f / (float)NN;
        float m = s * invn;
        float msq = q * invn;
        float g = gm[ch];
        float var = msq - 2.f * g * m * m + g * g * m * m;
        float sc = gw[ch] * rsqrtf(var + 1e-5f);
        ssc[ch] = sc;
        ssh[ch] = gb[ch] - sc * g * m;
    }
    __syncthreads();
    int i = blockIdx.x * blockDim.x + threadIdx.x;
    f16x8* h8 = (f16x8*)h;
    for (; i < nchunks; i += gridDim.x * blockDim.x) {
        f16x8 v = h8[i];
        int ch0 = (i * 8) & (FO - 1);
        float r[8];
        #pragma unroll
        for (int j = 0; j < 8; j++)
            r[j] = tanhf(ssc[ch0 + j] * (float)v[j] + ssh[ch0 + j]);
        if (OUT32) {
            ((float4*)out32)[i * 2]     = make_float4(r[0], r[1], r[2], r[3]);
            ((float4*)out32)[i * 2 + 1] = make_float4(r[4], r[5], r[6], r[7]);
        } else {
            float d = dinv[i / (FO / 8)];
            f16x8 o;
            #pragma unroll
            for (int j = 0; j < 8; j++) o[j] = (_Float16)(r[j] * d);
            h8[i] = o;
        }
    }
}

// ---------------- host side ----------------

static inline int ceil_div(int a, int b) { return (a + b - 1) / b; }

extern "C" void kernel_launch(void* const* d_in, const int* in_sizes, int n_in,
                              void* d_out, int out_size, void* d_ws, size_t ws_size,
                              hipStream_t stream) {
    const float* x = (const float*)d_in[0];
    const int* ei = (const int*)d_in[1];
    const float *Wp[4], *bp[4], *gwp[4], *gbp[4], *gmp[4];
    for (int i = 0; i < 4; i++) {
        Wp[i]  = (const float*)d_in[3 + 5 * i];
        bp[i]  = (const float*)d_in[4 + 5 * i];
        gwp[i] = (const float*)d_in[5 + 5 * i];
        gbp[i] = (const float*)d_in[6 + 5 * i];
        gmp[i] = (const float*)d_in[7 + 5 * i];
    }
    float* out = (float*)d_out;

    const int NT0 = ceil_div(NN, 32);    // 3125 layer-0 matmul blocks
    const int NTF = ceil_div(NN, 64);    // 1563 fused blocks (256 threads)

    char* p = (char*)d_ws;
    auto alloc = [&](size_t bytes) {
        void* q = (void*)p;
        p += (bytes + 255) / 256 * 256;
        return q;
    };
    int*      cnt2    = (int*)alloc((size_t)NN * 8 * 4);
    int*      cursor2 = (int*)alloc((size_t)NN * 8 * 4);
    int*      rowptr2 = (int*)alloc(((size_t)NN * 8 + 1) * 4);
    int*      cnt     = (int*)alloc((size_t)NN * 4);
    int*      rowptr  = (int*)alloc((size_t)(NN + 1) * 4);
    float*    dinv    = (float*)alloc((size_t)NN * 4);
    int*      ccol    = (int*)alloc((size_t)EE * 4);
    int*      bsum    = (int*)alloc((size_t)NB * 4);
    int*      boff    = (int*)alloc((size_t)NB * 4);
    int*      bhist   = (int*)alloc((size_t)NB * 64 * 4);
    int*      boff2   = (int*)alloc((size_t)NB * 64 * 4);
    int*      gstart  = (int*)alloc((size_t)64 * 4);
    int*      order   = (int*)alloc((size_t)NN * 4);
    float*    stats   = (float*)alloc((size_t)4 * 2 * NSPLIT * 128 * 4);
    _Float16* wt16    = (_Float16*)alloc((size_t)(128 * 64 + 2 * 128 * 128) * 2);
    _Float16* xs      = (_Float16*)alloc((size_t)NN * 8 * 2);
    _Float16* aggh    = (_Float16*)alloc((size_t)NN * 64 * 2);   // layer-0 agg only
    _Float16* hA      = (_Float16*)alloc((size_t)NN * 128 * 2);
    _Float16* hB      = (_Float16*)alloc((size_t)NN * 128 * 2);
    _Float16* wt16a   = wt16;
    _Float16* wt16b   = wt16 + 8192;
    _Float16* wt16c   = wt16 + 24576;

    // preprocessing (8 dispatches)
    k_init<<<512, 256, 0, stream>>>(cnt2, cursor2, stats, NN * 8);
    k_count2<<<2048, 256, 0, stream>>>(ei, cnt2, EE);
    k_prep1<<<NB, 256, 0, stream>>>(cnt2, cnt, dinv, bsum, bhist, NN);
    k_prep2<<<1, 128, 0, stream>>>(bsum, bhist, boff, boff2, gstart);
    k_prep3<<<NB, 256, 0, stream>>>(cnt, cnt2, boff, boff2, gstart, rowptr, rowptr2, order, NN);
    for (int pass = 0; pass < NPASS; pass++)
        k_scatter_pass<<<1024, 256, 0, stream>>>(ei, rowptr2, cursor2, ccol, EE, pass * RNGD);
    k_prep4<<<391 + 160, 256, 0, stream>>>(x, dinv, xs, Wp[1], Wp[2], Wp[3], wt16, NN);

    // layers (intermediates fp16, pre-scaled by dinv except final output)
    {   // layer 0: xs(8) -> aggh(8) -> hA(64)
        float* sp = stats + 0 * 2 * NSPLIT * 128;
        float* sq = sp + NSPLIT * 128;
        k_spmm8<<<ceil_div(NN, 256), 256, 0, stream>>>(xs, order, rowptr, ccol, dinv, aggh, NN);
        k_mm<8, 64><<<NT0, 256, 0, stream>>>(aggh, Wp[0], bp[0], hA, sp, sq, NN);
        k_normc<false, 64><<<1024, 256, 0, stream>>>(hA, nullptr, sp, sq, gwp[0], gbp[0], gmp[0], dinv, NN * 64 / 8);
    }
    {   // layer 1: hA(64) --fused gather+mfma--> hB(128)
        float* sp = stats + 1 * 2 * NSPLIT * 128;
        float* sq = sp + NSPLIT * 128;
        k_fused<64><<<NTF, 256, 0, stream>>>(hA, order, rowptr, ccol, dinv, wt16a, bp[1], hB, sp, sq, NN);
        k_normc<false, 128><<<1024, 256, 0, stream>>>(hB, nullptr, sp, sq, gwp[1], gbp[1], gmp[1], dinv, NN * 128 / 8);
    }
    {   // layer 2: hB(128) --fused--> hA(128)
        float* sp = stats + 2 * 2 * NSPLIT * 128;
        float* sq = sp + NSPLIT * 128;
        k_fused<128><<<NTF, 256, 0, stream>>>(hB, order, rowptr, ccol, dinv, wt16b, bp[2], hA, sp, sq, NN);
        k_normc<false, 128><<<1024, 256, 0, stream>>>(hA, nullptr, sp, sq, gwp[2], gbp[2], gmp[2], dinv, NN * 128 / 8);
    }
    {   // layer 3: hA(128) --fused--> hB(128) -> d_out (fp32, unscaled)
        float* sp = stats + 3 * 2 * NSPLIT * 128;
        float* sq = sp + NSPLIT * 128;
        k_fused<128><<<NTF, 256, 0, stream>>>(hA, order, rowptr, ccol, dinv, wt16c, bp[3], hB, sp, sq, NN);
        k_normc<true, 128><<<1024, 256, 0, stream>>>(hB, out, sp, sq, gwp[3], gbp[3], gmp[3], dinv, NN * 128 / 8);
    }
}

// Round 18
// 492.284 us; speedup vs baseline: 1.1182x; 1.0044x over previous
//
#include <hip/hip_runtime.h>
#include <hip/hip_bf16.h>
#include <hip/hip_fp16.h>

#define NN 100000
#define EE 1600000
#define NB 98         // ceil(NN / 1024)
#define NPASS 2       // scatter destination passes
#define RNGD 50000    // NN / NPASS
#define NBUCK 8       // source-column buckets (sorted CSR improves row-local L2 reuse)
#define BUCKW 12500   // NN / NBUCK
#define NSPLIT 32     // stats atomic-split ways

typedef _Float16 f16x8 __attribute__((ext_vector_type(8)));
typedef _Float16 f16x4 __attribute__((ext_vector_type(4)));
typedef float f32x4 __attribute__((ext_vector_type(4)));

// ---------------- graph preprocessing ----------------

__global__ void k_init(int* __restrict__ cnt2, int* __restrict__ cursor2,
                       float* __restrict__ stats, int n8) {
    int i = blockIdx.x * blockDim.x + threadIdx.x;
    for (; i < n8; i += gridDim.x * blockDim.x) {
        cnt2[i] = 0;
        cursor2[i] = 0;
        if (i < 4 * 2 * NSPLIT * 128) stats[i] = 0.0f;   // 4 layers x {sum,sq} x 32 x 128
    }
}

// count per (row, col-bucket)
__global__ void k_count2(const int* __restrict__ ei, int* __restrict__ cnt2, int e_total) {
    int e = blockIdx.x * blockDim.x + threadIdx.x;
    for (; e < e_total; e += gridDim.x * blockDim.x) {
        int r = ei[e];
        int c = ei[e_total + e];
        atomicAdd(&cnt2[r * NBUCK + c / BUCKW], 1);
    }
}

// prep1: per 1024-node chunk -> cnt, dinv, bsum (chunk degree total),
// bhist (degree histogram, TRANSPOSED bhist[d*NB+blk])
__global__ __launch_bounds__(256) void k_prep1(const int* __restrict__ cnt2,
                                               int* __restrict__ cnt,
                                               float* __restrict__ dinv,
                                               int* __restrict__ bsum,
                                               int* __restrict__ bhist, int n) {
    __shared__ int hist[64];
    __shared__ int ws[4];
    int blk = blockIdx.x, tid = threadIdx.x;
    if (tid < 64) hist[tid] = 0;
    __syncthreads();
    int idx = blk * 1024 + tid * 4;
    int stot = 0;
    #pragma unroll
    for (int j = 0; j < 4; j++) {
        int node = idx + j;
        if (node < n) {
            int4 a = *(const int4*)&cnt2[node * 8];
            int4 b = *(const int4*)&cnt2[node * 8 + 4];
            int s = a.x + a.y + a.z + a.w + b.x + b.y + b.z + b.w;
            cnt[node] = s;
            dinv[node] = rsqrtf((float)(s + 1));
            atomicAdd(&hist[min(s, 63)], 1);
            stot += s;
        }
    }
    #pragma unroll
    for (int off = 32; off; off >>= 1) stot += __shfl_down(stot, off, 64);
    if ((tid & 63) == 0) ws[tid >> 6] = stot;
    __syncthreads();
    if (tid == 0) bsum[blk] = ws[0] + ws[1] + ws[2] + ws[3];
    if (tid < 64) bhist[tid * NB + blk] = hist[tid];
}

// prep2 (single block, 128 threads): scan bsum -> boff; scan bhist -> boff2, gstart
__global__ __launch_bounds__(128) void k_prep2(const int* __restrict__ bsum,
                                               const int* __restrict__ bhist,
                                               int* __restrict__ boff,
                                               int* __restrict__ boff2,
                                               int* __restrict__ gstart) {
    __shared__ int w0sum;
    int tid = threadIdx.x;
    int lane = tid & 63;
    {   // exclusive scan of NB block sums
        int v = (tid < NB) ? bsum[tid] : 0;
        int incl = v;
        #pragma unroll
        for (int off = 1; off < 64; off <<= 1) {
            int t = __shfl_up(incl, off, 64);
            if (lane >= off) incl += t;
        }
        if (tid == 63) w0sum = incl;
        __syncthreads();
        int excl = incl - v + ((tid >= 64) ? w0sum : 0);
        if (tid < NB) boff[tid] = excl;
    }
    if (tid < 64) {   // per-degree running offsets + global degree starts
        int d = tid;
        int running = 0;
        for (int b = 0; b < NB; b++) {
            int v = bhist[d * NB + b];
            boff2[b * 64 + d] = running;
            running += v;
        }
        int incl = running;
        #pragma unroll
        for (int off = 1; off < 64; off <<= 1) {
            int t = __shfl_up(incl, off, 64);
            if (d >= off) incl += t;
        }
        gstart[d] = incl - running;
    }
}

// prep3: per 1024-node chunk -> rowptr, rowptr2 (bucket offsets), order (counting sort)
__global__ __launch_bounds__(256) void k_prep3(const int* __restrict__ cnt,
                                               const int* __restrict__ cnt2,
                                               const int* __restrict__ boff,
                                               const int* __restrict__ boff2,
                                               const int* __restrict__ gstart,
                                               int* __restrict__ rowptr,
                                               int* __restrict__ rowptr2,
                                               int* __restrict__ order, int n) {
    __shared__ int wsum[4];
    __shared__ int cur[64];
    int blk = blockIdx.x, tid = threadIdx.x, lane = tid & 63, wid = tid >> 6;
    if (tid < 64) cur[tid] = 0;
    int idx = blk * 1024 + tid * 4;
    int c[4]; int s = 0;
    #pragma unroll
    for (int j = 0; j < 4; j++) { c[j] = (idx + j < n) ? cnt[idx + j] : 0; s += c[j]; }
    int incl = s;
    #pragma unroll
    for (int off = 1; off < 64; off <<= 1) {
        int t = __shfl_up(incl, off, 64);
        if (lane >= off) incl += t;
    }
    if (lane == 63) wsum[wid] = incl;
    __syncthreads();
    int wpre = 0;
    #pragma unroll
    for (int w = 0; w < 4; w++) if (w < wid) wpre += wsum[w];
    int base = boff[blk] + wpre + (incl - s);
    #pragma unroll
    for (int j = 0; j < 4; j++) {
        int node = idx + j;
        if (node < n) {
            int rstart = base;
            base += c[j];
            rowptr[node + 1] = base;
            int4 a = *(const int4*)&cnt2[node * 8];
            int4 b = *(const int4*)&cnt2[node * 8 + 4];
            int v[8] = {a.x, a.y, a.z, a.w, b.x, b.y, b.z, b.w};
            int o[8];
            #pragma unroll
            for (int i = 0; i < 8; i++) { o[i] = rstart; rstart += v[i]; }
            *(int4*)&rowptr2[node * 8]     = make_int4(o[0], o[1], o[2], o[3]);
            *(int4*)&rowptr2[node * 8 + 4] = make_int4(o[4], o[5], o[6], o[7]);
            if (node == n - 1) rowptr2[n * 8] = rstart;
        }
    }
    if (blk == 0 && tid == 0) rowptr[0] = 0;
    __syncthreads();
    #pragma unroll
    for (int j = 0; j < 4; j++) {
        int node = idx + j;
        if (node < n) {
            int d = min(c[j], 63);
            int r = atomicAdd(&cur[d], 1);
            order[gstart[d] + boff2[blk * 64 + d] + r] = node;
        }
    }
}

// scatter pass: destinations in [lo, lo+RNGD), into bucketed slots
__global__ void k_scatter_pass(const int* __restrict__ ei, const int* __restrict__ rowptr2,
                               int* __restrict__ cursor2, int* __restrict__ ccol,
                               int e_total, int lo) {
    int hi = lo + RNGD;
    int e = blockIdx.x * blockDim.x + threadIdx.x;
    for (; e < e_total; e += gridDim.x * blockDim.x) {
        int r = ei[e];
        if (r >= lo && r < hi) {
            int c = ei[e_total + e];
            int idx = r * NBUCK + c / BUCKW;
            int pos = rowptr2[idx] + atomicAdd(&cursor2[idx], 1);
            ccol[pos] = c;
        }
    }
}

// prep4: prescale x -> xs (blocks 0..390) and W^T fp16 for all layers (rest)
// wt16 layout: [0..8191]=W1^T(128x64), [8192..24575]=W2^T, [24576..40959]=W3^T,
//              [40960..41471]=W0^T (64ch x 8k)
__global__ __launch_bounds__(256) void k_prep4(const float* __restrict__ x,
                                               const float* __restrict__ dinv,
                                               _Float16* __restrict__ xs,
                                               const float* __restrict__ W0,
                                               const float* __restrict__ W1,
                                               const float* __restrict__ W2,
                                               const float* __restrict__ W3,
                                               _Float16* __restrict__ wt16, int n) {
    int blk = blockIdx.x;
    if (blk < 391) {
        int node = blk * 256 + threadIdx.x;
        if (node >= n) return;
        float d = dinv[node];
        float4 a = ((const float4*)x)[node * 2];
        float4 b = ((const float4*)x)[node * 2 + 1];
        f16x8 o;
        o[0] = (_Float16)(a.x * d); o[1] = (_Float16)(a.y * d);
        o[2] = (_Float16)(a.z * d); o[3] = (_Float16)(a.w * d);
        o[4] = (_Float16)(b.x * d); o[5] = (_Float16)(b.y * d);
        o[6] = (_Float16)(b.z * d); o[7] = (_Float16)(b.w * d);
        ((f16x8*)xs)[node] = o;
    } else {
        int wi = (blk - 391) * 256 + threadIdx.x;   // 0..41471
        if (wi < 8192) {
            int k = wi / 128, ch = wi % 128;
            wt16[ch * 64 + k] = (_Float16)W1[wi];
        } else if (wi < 24576) {
            int local = wi - 8192;
            int k = local / 128, ch = local % 128;
            wt16[8192 + ch * 128 + k] = (_Float16)W2[local];
        } else if (wi < 40960) {
            int local = wi - 24576;
            int k = local / 128, ch = local % 128;
            wt16[24576 + ch * 128 + k] = (_Float16)W3[local];
        } else if (wi < 41472) {
            int local = wi - 40960;        // 0..511
            int k = local / 64, ch = local % 64;
            wt16[40960 + ch * 8 + k] = (_Float16)W0[local];
        }
    }
}

// ---------------- FUSED layer 0: gather xs (FI=8) + MFMA (FO=64) ----------------
// Wave = 16 nodes. All 64 lanes gather: lh-quadrant takes edges k = s+lh, step 4;
// cross-lh shfl_xor reduce. B-frag: K=8 real rows (lh==0), rows 8..31 zero.
// A = W0^T read directly from global (1KB, L1-hot). Stats FO=64, split atomics.

__global__ __launch_bounds__(256) void k_fused8(const _Float16* __restrict__ xs,
                                                const int* __restrict__ order,
                                                const int* __restrict__ rowptr,
                                                const int* __restrict__ ccol,
                                                const float* __restrict__ dinv,
                                                const _Float16* __restrict__ wt0,
                                                const float* __restrict__ b,
                                                _Float16* __restrict__ hout,
                                                float* __restrict__ psum,
                                                float* __restrict__ psq, int n) {
    __shared__ float red[2 * 4 * 64];    // [{sum,sq}][wave][ch] = 2KB

    const int tid = threadIdx.x;
    const int wv  = tid >> 6;
    const int ln  = tid & 63;
    const int l15 = ln & 15;
    const int lh  = ln >> 4;

    const int gid = blockIdx.x * 64 + wv * 16 + l15;
    const bool v0 = (gid < n);
    const int node = v0 ? order[gid] : 0;
    const f16x8* x8 = (const f16x8*)xs;

    float acc8[8];
    #pragma unroll
    for (int j = 0; j < 8; j++) acc8[j] = 0.f;
    if (v0) {
        if (lh == 0) {
            f16x8 s8 = x8[node];
            #pragma unroll
            for (int j = 0; j < 8; j++) acc8[j] += (float)s8[j];
        }
        int s = rowptr[node], e = rowptr[node + 1];
        for (int k = s + lh; k < e; k += 4) {
            f16x8 v = x8[ccol[k]];
            #pragma unroll
            for (int j = 0; j < 8; j++) acc8[j] += (float)v[j];
        }
    }
    // reduce across lh quadrants (lanes ^16, ^32); all lanes end with full sum
    #pragma unroll
    for (int m = 16; m < 64; m <<= 1) {
        #pragma unroll
        for (int j = 0; j < 8; j++) acc8[j] += __shfl_xor(acc8[j], m, 64);
    }
    float dr = v0 ? dinv[node] : 0.f;
    f16x8 bf = {};
    if (lh == 0) {
        #pragma unroll
        for (int j = 0; j < 8; j++) bf[j] = (_Float16)(acc8[j] * dr);
    }

    f32x4 acc[4];
    #pragma unroll
    for (int t = 0; t < 4; t++) acc[t] = *(const f32x4*)&b[t * 16 + lh * 4];

    #pragma unroll
    for (int t = 0; t < 4; t++) {
        f16x8 af = {};
        if (lh == 0) af = *(const f16x8*)&wt0[(t * 16 + l15) * 8];
        acc[t] = __builtin_amdgcn_mfma_f32_16x16x32_f16(af, bf, acc[t], 0, 0, 0);
    }

    // store (ch = t*16 + lh*4 + r, 64 channels)
    if (v0) {
        #pragma unroll
        for (int t = 0; t < 4; t++) {
            f16x4 o;
            #pragma unroll
            for (int r = 0; r < 4; r++) o[r] = (_Float16)acc[t][r];
            ((f16x4*)hout)[(size_t)node * 16 + t * 4 + lh] = o;
        }
    }

    // stats
    #pragma unroll
    for (int t = 0; t < 4; t++) {
        f32x4 sv = {0.f, 0.f, 0.f, 0.f}, qv = {0.f, 0.f, 0.f, 0.f};
        if (v0) { sv = acc[t]; qv = acc[t] * acc[t]; }
        #pragma unroll
        for (int m = 1; m < 16; m <<= 1) {
            #pragma unroll
            for (int r = 0; r < 4; r++) {
                sv[r] += __shfl_xor(sv[r], m, 64);
                qv[r] += __shfl_xor(qv[r], m, 64);
            }
        }
        if (l15 == 0) {
            *(f32x4*)&red[wv * 64 + t * 16 + lh * 4] = sv;
            *(f32x4*)&red[256 + wv * 64 + t * 16 + lh * 4] = qv;
        }
    }
    __syncthreads();
    if (tid < 64) {
        float ss = red[tid] + red[64 + tid] + red[128 + tid] + red[192 + tid];
        float qq = red[256 + tid] + red[320 + tid] + red[384 + tid] + red[448 + tid];
        int split = blockIdx.x & (NSPLIT - 1);
        atomicAdd(&psum[split * 64 + tid], ss);
        atomicAdd(&psq [split * 64 + tid], qq);
    }
}

// ---------------- FUSED gather + MFMA matmul, FO=128, FI in {64,128} ------------
// r14 configuration (measured best: fused<128>=90us): 256 threads, ascending
// sorted-contiguous node = order[gid]; W^T fp16 staged coalesced into
// XOR-swizzled LDS (32KB, conflict-free); 'red' aliases wt after last MFMA read.

template <int FI>
__global__ __launch_bounds__(256) void k_fused(const _Float16* __restrict__ h,
                                               const int* __restrict__ order,
                                               const int* __restrict__ rowptr,
                                               const int* __restrict__ ccol,
                                               const float* __restrict__ dinv,
                                               const _Float16* __restrict__ wt16,
                                               const float* __restrict__ b,
                                               _Float16* __restrict__ hout,
                                               float* __restrict__ psum,
                                               float* __restrict__ psq, int n) {
    constexpr int KS = FI / 32;          // K-steps of 32
    constexpr int TPN = FI / 8;          // 16B chunks per row
    __shared__ _Float16 wt[128 * FI];    // swizzled W^T; aliased as red later

    const int tid = threadIdx.x;
    const int wv  = tid >> 6;
    const int ln  = tid & 63;
    const int l15 = ln & 15;
    const int lh  = ln >> 4;             // 0..3

    // stage swizzled W^T (coalesced 16B copies)
    {
        const f16x8* wg = (const f16x8*)wt16;
        f16x8* wl = (f16x8*)wt;
        for (int idx = tid; idx < 128 * TPN; idx += 256) {
            int ch = idx / TPN, c = idx % TPN;
            wl[ch * TPN + (c ^ (ch & 7))] = wg[idx];
        }
    }

    const int gid = blockIdx.x * 64 + wv * 16 + l15;
    const bool v0 = (gid < n);
    const int node = v0 ? order[gid] : 0;
    const f16x8* h8 = (const f16x8*)h;

    // gather aggregation in fp32, B-frag layout (k = kk*32 + lh*8 + j)
    float ga[KS][8];
    int s = 0, e = 0;
    if (v0) { s = rowptr[node]; e = rowptr[node + 1]; }
    #pragma unroll
    for (int kk = 0; kk < KS; kk++) {       // self contribution
        f16x8 v = {};
        if (v0) v = h8[(size_t)node * TPN + kk * 4 + lh];
        #pragma unroll
        for (int j = 0; j < 8; j++) ga[kk][j] = (float)v[j];
    }
    for (int k = s; k < e; k++) {
        int c = ccol[k];
        #pragma unroll
        for (int kk = 0; kk < KS; kk++) {
            f16x8 v = h8[(size_t)c * TPN + kk * 4 + lh];
            #pragma unroll
            for (int j = 0; j < 8; j++) ga[kk][j] += (float)v[j];
        }
    }
    float dr = v0 ? dinv[node] : 0.f;
    f16x8 bf[KS];
    #pragma unroll
    for (int kk = 0; kk < KS; kk++) {
        #pragma unroll
        for (int j = 0; j < 8; j++) bf[kk][j] = (_Float16)(ga[kk][j] * dr);
    }

    // acc init = bias (ch = t*16 + lh*4 + r)
    f32x4 acc[8];
    #pragma unroll
    for (int t = 0; t < 8; t++) acc[t] = *(const f32x4*)&b[t * 16 + lh * 4];

    __syncthreads();   // wt staged

    #pragma unroll
    for (int kk = 0; kk < KS; kk++) {
        #pragma unroll
        for (int t = 0; t < 8; t++) {
            f16x8 af = ((const f16x8*)wt)[(t * 16 + l15) * TPN + ((kk * 4 + lh) ^ (l15 & 7))];
            acc[t] = __builtin_amdgcn_mfma_f32_16x16x32_f16(af, bf[kk], acc[t], 0, 0, 0);
        }
    }

    // stores (no LDS involved)
    if (v0) {
        #pragma unroll
        for (int t = 0; t < 8; t++) {
            f16x4 o;
            #pragma unroll
            for (int r = 0; r < 4; r++) o[r] = (_Float16)acc[t][r];
            ((f16x4*)hout)[(size_t)node * 32 + t * 4 + lh] = o;
        }
    }

    __syncthreads();   // all wt reads done -> safe to alias as red
    float* red = (float*)wt;   // [2][4][128] floats = 4KB
    #pragma unroll
    for (int t = 0; t < 8; t++) {
        f32x4 sv = {0.f, 0.f, 0.f, 0.f}, qv = {0.f, 0.f, 0.f, 0.f};
        if (v0) { sv = acc[t]; qv = acc[t] * acc[t]; }
        #pragma unroll
        for (int m = 1; m < 16; m <<= 1) {
            #pragma unroll
            for (int r = 0; r < 4; r++) {
                sv[r] += __shfl_xor(sv[r], m, 64);
                qv[r] += __shfl_xor(qv[r], m, 64);
            }
        }
        if (l15 == 0) {
            *(f32x4*)&red[wv * 128 + t * 16 + lh * 4] = sv;
            *(f32x4*)&red[512 + wv * 128 + t * 16 + lh * 4] = qv;
        }
    }
    __syncthreads();
    if (tid < 128) {
        float ss = red[tid] + red[128 + tid] + red[256 + tid] + red[384 + tid];
        float qq = red[512 + tid] + red[640 + tid] + red[768 + tid] + red[896 + tid];
        int split = blockIdx.x & (NSPLIT - 1);
        atomicAdd(&psum[split * 128 + tid], ss);
        atomicAdd(&psq [split * 128 + tid], qq);
    }
}

// ------- norm + tanh with INLINE coef (each block reduces the 32 partial rows;
// L2-hot read). Non-final layers pre-scale by dinv; final writes fp32. -------

template <bool OUT32, int FO>
__global__ __launch_bounds__(256) void k_normc(_Float16* __restrict__ h,
                                               float* __restrict__ out32,
                                               const float* __restrict__ psum,
                                               const float* __restrict__ psq,
                                               const float* __restrict__ gw,
                                               const float* __restrict__ gb,
                                               const float* __restrict__ gm,
                                               const float* __restrict__ dinv,
                                               int nchunks) {
    __shared__ float ssc[128], ssh[128];
    if (threadIdx.x < FO) {
        int ch = threadIdx.x;
        float s = 0.f, q = 0.f;
        #pragma unroll 8
        for (int r = 0; r < NSPLIT; r++) {
            s += psum[r * FO + ch];
            q += psq[r * FO + ch];
        }
        float invn = 1.0f / (float)NN;
        float m = s * invn;
        float msq = q * invn;
        float g = gm[ch];
        float var = msq - 2.f * g * m * m + g * g * m * m;
        float sc = gw[ch] * rsqrtf(var + 1e-5f);
        ssc[ch] = sc;
        ssh[ch] = gb[ch] - sc * g * m;
    }
    __syncthreads();
    int i = blockIdx.x * blockDim.x + threadIdx.x;
    f16x8* h8 = (f16x8*)h;
    for (; i < nchunks; i += gridDim.x * blockDim.x) {
        f16x8 v = h8[i];
        int ch0 = (i * 8) & (FO - 1);
        float r[8];
        #pragma unroll
        for (int j = 0; j < 8; j++)
            r[j] = tanhf(ssc[ch0 + j] * (float)v[j] + ssh[ch0 + j]);
        if (OUT32) {
            ((float4*)out32)[i * 2]     = make_float4(r[0], r[1], r[2], r[3]);
            ((float4*)out32)[i * 2 + 1] = make_float4(r[4], r[5], r[6], r[7]);
        } else {
            float d = dinv[i / (FO / 8)];
            f16x8 o;
            #pragma unroll
            for (int j = 0; j < 8; j++) o[j] = (_Float16)(r[j] * d);
            h8[i] = o;
        }
    }
}

// ---------------- host side ----------------

static inline int ceil_div(int a, int b) { return (a + b - 1) / b; }

extern "C" void kernel_launch(void* const* d_in, const int* in_sizes, int n_in,
                              void* d_out, int out_size, void* d_ws, size_t ws_size,
                              hipStream_t stream) {
    const float* x = (const float*)d_in[0];
    const int* ei = (const int*)d_in[1];
    const float *Wp[4], *bp[4], *gwp[4], *gbp[4], *gmp[4];
    for (int i = 0; i < 4; i++) {
        Wp[i]  = (const float*)d_in[3 + 5 * i];
        bp[i]  = (const float*)d_in[4 + 5 * i];
        gwp[i] = (const float*)d_in[5 + 5 * i];
        gbp[i] = (const float*)d_in[6 + 5 * i];
        gmp[i] = (const float*)d_in[7 + 5 * i];
    }
    float* out = (float*)d_out;

    const int NTF = ceil_div(NN, 64);    // 1563 fused blocks (256 threads)

    char* p = (char*)d_ws;
    auto alloc = [&](size_t bytes) {
        void* q = (void*)p;
        p += (bytes + 255) / 256 * 256;
        return q;
    };
    int*      cnt2    = (int*)alloc((size_t)NN * 8 * 4);
    int*      cursor2 = (int*)alloc((size_t)NN * 8 * 4);
    int*      rowptr2 = (int*)alloc(((size_t)NN * 8 + 1) * 4);
    int*      cnt     = (int*)alloc((size_t)NN * 4);
    int*      rowptr  = (int*)alloc((size_t)(NN + 1) * 4);
    float*    dinv    = (float*)alloc((size_t)NN * 4);
    int*      ccol    = (int*)alloc((size_t)EE * 4);
    int*      bsum    = (int*)alloc((size_t)NB * 4);
    int*      boff    = (int*)alloc((size_t)NB * 4);
    int*      bhist   = (int*)alloc((size_t)NB * 64 * 4);
    int*      boff2   = (int*)alloc((size_t)NB * 64 * 4);
    int*      gstart  = (int*)alloc((size_t)64 * 4);
    int*      order   = (int*)alloc((size_t)NN * 4);
    float*    stats   = (float*)alloc((size_t)4 * 2 * NSPLIT * 128 * 4);
    _Float16* wt16    = (_Float16*)alloc((size_t)41472 * 2);
    _Float16* xs      = (_Float16*)alloc((size_t)NN * 8 * 2);
    _Float16* hA      = (_Float16*)alloc((size_t)NN * 128 * 2);
    _Float16* hB      = (_Float16*)alloc((size_t)NN * 128 * 2);
    _Float16* wt16a   = wt16;
    _Float16* wt16b   = wt16 + 8192;
    _Float16* wt16c   = wt16 + 24576;
    _Float16* wt16z   = wt16 + 40960;   // W0^T

    // preprocessing (7 dispatches)
    k_init<<<512, 256, 0, stream>>>(cnt2, cursor2, stats, NN * 8);
    k_count2<<<2048, 256, 0, stream>>>(ei, cnt2, EE);
    k_prep1<<<NB, 256, 0, stream>>>(cnt2, cnt, dinv, bsum, bhist, NN);
    k_prep2<<<1, 128, 0, stream>>>(bsum, bhist, boff, boff2, gstart);
    k_prep3<<<NB, 256, 0, stream>>>(cnt, cnt2, boff, boff2, gstart, rowptr, rowptr2, order, NN);
    for (int pass = 0; pass < NPASS; pass++)
        k_scatter_pass<<<1024, 256, 0, stream>>>(ei, rowptr2, cursor2, ccol, EE, pass * RNGD);
    k_prep4<<<391 + 162, 256, 0, stream>>>(x, dinv, xs, Wp[0], Wp[1], Wp[2], Wp[3], wt16, NN);

    // layers (intermediates fp16, pre-scaled by dinv except final output)
    {   // layer 0: xs(8) --fused gather+mfma--> hA(64)
        float* sp = stats + 0 * 2 * NSPLIT * 128;
        float* sq = sp + NSPLIT * 128;
        k_fused8<<<NTF, 256, 0, stream>>>(xs, order, rowptr, ccol, dinv, wt16z, bp[0], hA, sp, sq, NN);
        k_normc<false, 64><<<1024, 256, 0, stream>>>(hA, nullptr, sp, sq, gwp[0], gbp[0], gmp[0], dinv, NN * 64 / 8);
    }
    {   // layer 1: hA(64) --fused--> hB(128)
        float* sp = stats + 1 * 2 * NSPLIT * 128;
        float* sq = sp + NSPLIT * 128;
        k_fused<64><<<NTF, 256, 0, stream>>>(hA, order, rowptr, ccol, dinv, wt16a, bp[1], hB, sp, sq, NN);
        k_normc<false, 128><<<1024, 256, 0, stream>>>(hB, nullptr, sp, sq, gwp[1], gbp[1], gmp[1], dinv, NN * 128 / 8);
    }
    {   // layer 2: hB(128) --fused--> hA(128)
        float* sp = stats + 2 * 2 * NSPLIT * 128;
        float* sq = sp + NSPLIT * 128;
        k_fused<128><<<NTF, 256, 0, stream>>>(hB, order, rowptr, ccol, dinv, wt16b, bp[2], hA, sp, sq, NN);
        k_normc<false, 128><<<1024, 256, 0, stream>>>(hA, nullptr, sp, sq, gwp[2], gbp[2], gmp[2], dinv, NN * 128 / 8);
    }
    {   // layer 3: hA(128) --fused--> hB(128) -> d_out (fp32, unscaled)
        float* sp = stats + 3 * 2 * NSPLIT * 128;
        float* sq = sp + NSPLIT * 128;
        k_fused<128><<<NTF, 256, 0, stream>>>(hA, order, rowptr, ccol, dinv, wt16c, bp[3], hB, sp, sq, NN);
        k_normc<true, 128><<<1024, 256, 0, stream>>>(hB, out, sp, sq, gwp[3], gbp[3], gmp[3], dinv, NN * 128 / 8);
    }
}